// Round 6
// baseline (156.427 us; speedup 1.0000x reference)
//
#include <hip/hip_runtime.h>

#define NN 50000
#define EE 800000
#define ETOT (EE + NN)
#define MAXD 96      // max degree on fast path (Poisson(16)+1 -> max ~60)
#define NBK 196      // dst buckets of 256 nodes
#define CAP 6144     // records per bucket slot (mean 4352, +28 sigma)
#define CHX 2304     // edges per xcast block (9*256); 391 blocks cover ETOT
#define TM 32        // dst rows per fused block

typedef _Float16 f16x8 __attribute__((ext_vector_type(8)));
typedef _Float16 f16x2 __attribute__((ext_vector_type(2)));
typedef float f32x4 __attribute__((ext_vector_type(4)));
typedef float f32x2 __attribute__((ext_vector_type(2)));
typedef unsigned int u32x4 __attribute__((ext_vector_type(4)));

__device__ __forceinline__ float lrelu(float v) { return v > 0.f ? v : 0.2f * v; }
__device__ __forceinline__ unsigned int pack2(float a, float b) {
  unsigned short lo = __builtin_bit_cast(unsigned short, (_Float16)a);
  unsigned short hi = __builtin_bit_cast(unsigned short, (_Float16)b);
  return (unsigned int)lo | ((unsigned int)hi << 16);
}

// ---------------------------------------------------------------------------
// Prep: Bt[col][k] fp16 (k = h*128+c), folded attention WaS/WaD, zero bcnt.
// ---------------------------------------------------------------------------
__global__ void k_prep(const float* __restrict__ W,
                       const float* __restrict__ att_s,
                       const float* __restrict__ att_d,
                       unsigned short* __restrict__ Bt,
                       float* __restrict__ WaS, float* __restrict__ WaD,
                       int* __restrict__ bcnt) {
  int gid = blockIdx.x * blockDim.x + threadIdx.x;
  if (gid < NBK) bcnt[gid] = 0;
  if (gid < 128 * 512) {
    int col = gid >> 9, k = gid & 511;
    float v = W[(k & 127) * 512 + (k >> 7) * 128 + col];
    _Float16 hv = (_Float16)v;
    Bt[col * 512 + k] = __builtin_bit_cast(unsigned short, hv);
  }
  if (gid < 512) {
    int k = gid >> 2, h = gid & 3;
    const float* wrow = W + k * 512 + h * 128;
    const float* as = att_s + h * 128;
    const float* ad = att_d + h * 128;
    float ss = 0.f, sd = 0.f;
    for (int c = 0; c < 128; ++c) { float w = wrow[c]; ss += w * as[c]; sd += w * ad[c]; }
    WaS[k * 4 + h] = ss;
    WaD[k * 4 + h] = sd;
  }
}

// ---------------------------------------------------------------------------
// Fused: x->fp16 xh + a_s/a_d (LDS-staged, 2 thr/node)  AND  pass-1 coarse
// binning of edge records (src | d_local<<16) into 196 bucket slots.
// ---------------------------------------------------------------------------
__global__ __launch_bounds__(256) void k_xcast_p1(const float* __restrict__ x,
                                                  const float* __restrict__ WaS,
                                                  const float* __restrict__ WaD,
                                                  const int* __restrict__ ei,
                                                  unsigned int* __restrict__ xh,
                                                  float* __restrict__ a_s,
                                                  float* __restrict__ a_d,
                                                  int* __restrict__ bcnt,
                                                  unsigned int* __restrict__ ebuf) {
  __shared__ unsigned long long D[128][33];
  __shared__ float4 wsl[128];
  __shared__ float4 wdl[128];
  __shared__ int cnt[NBK];
  __shared__ int gbase[NBK];
  int t = threadIdx.x;
  int nb = blockIdx.x * 128;
  if (t < 128) wsl[t] = ((const float4*)WaS)[t];
  else wdl[t - 128] = ((const float4*)WaD)[t - 128];
  for (int i = t; i < NBK; i += 256) cnt[i] = 0;

#pragma unroll
  for (int i = 0; i < 16; ++i) {
    int idx = t + i * 256;
    int n = idx >> 5, c4 = idx & 31;
    int gn = nb + n;
    float4 v = make_float4(0.f, 0.f, 0.f, 0.f);
    if (gn < NN) v = ((const float4*)x)[(size_t)gn * 32 + c4];
    unsigned int lo = pack2(v.x, v.y);
    unsigned int hi = pack2(v.z, v.w);
    if (gn < NN) ((uint2*)xh)[(size_t)gn * 32 + c4] = make_uint2(lo, hi);
    D[n][c4] = (unsigned long long)lo | ((unsigned long long)hi << 32);
  }
  __syncthreads();

  {
    int n = t >> 1, half = t & 1;
    float s0 = 0.f, s1 = 0.f, s2 = 0.f, s3 = 0.f;
    float d0 = 0.f, d1 = 0.f, d2 = 0.f, d3 = 0.f;
#pragma unroll
    for (int p = 0; p < 16; ++p) {
      int c4 = 2 * p + half;
      unsigned long long q = D[n][c4];
      f16x2 lo2 = __builtin_bit_cast(f16x2, (unsigned int)q);
      f16x2 hi2 = __builtin_bit_cast(f16x2, (unsigned int)(q >> 32));
      float f0 = (float)lo2[0], f1 = (float)lo2[1];
      float f2 = (float)hi2[0], f3 = (float)hi2[1];
      int c = c4 * 4;
      float4 w0 = wsl[c], w1 = wsl[c + 1], w2 = wsl[c + 2], w3 = wsl[c + 3];
      s0 += f0 * w0.x + f1 * w1.x + f2 * w2.x + f3 * w3.x;
      s1 += f0 * w0.y + f1 * w1.y + f2 * w2.y + f3 * w3.y;
      s2 += f0 * w0.z + f1 * w1.z + f2 * w2.z + f3 * w3.z;
      s3 += f0 * w0.w + f1 * w1.w + f2 * w2.w + f3 * w3.w;
      float4 v0 = wdl[c], v1 = wdl[c + 1], v2 = wdl[c + 2], v3 = wdl[c + 3];
      d0 += f0 * v0.x + f1 * v1.x + f2 * v2.x + f3 * v3.x;
      d1 += f0 * v0.y + f1 * v1.y + f2 * v2.y + f3 * v3.y;
      d2 += f0 * v0.z + f1 * v1.z + f2 * v2.z + f3 * v3.z;
      d3 += f0 * v0.w + f1 * v1.w + f2 * v2.w + f3 * v3.w;
    }
    s0 += __shfl_xor(s0, 1); s1 += __shfl_xor(s1, 1);
    s2 += __shfl_xor(s2, 1); s3 += __shfl_xor(s3, 1);
    d0 += __shfl_xor(d0, 1); d1 += __shfl_xor(d1, 1);
    d2 += __shfl_xor(d2, 1); d3 += __shfl_xor(d3, 1);
    int gn = nb + n;
    if (half == 0 && gn < NN) {
      *(float4*)(a_s + gn * 4) = make_float4(s0, s1, s2, s3);
      *(float4*)(a_d + gn * 4) = make_float4(d0, d1, d2, d3);
    }
  }

  // ---- pass 1: coarse dst-binning (cnt[] zeroed before first barrier)
  int e0 = blockIdx.x * CHX;
#pragma unroll
  for (int k = 0; k < CHX / 256; ++k) {
    int e = e0 + t + k * 256;
    if (e < ETOT) {
      int d = (e < EE) ? ei[EE + e] : (e - EE);
      atomicAdd(&cnt[d >> 8], 1);
    }
  }
  __syncthreads();
  for (int i = t; i < NBK; i += 256) {
    gbase[i] = (cnt[i] > 0) ? atomicAdd(&bcnt[i], cnt[i]) : 0;
    cnt[i] = 0;
  }
  __syncthreads();
#pragma unroll
  for (int k = 0; k < CHX / 256; ++k) {
    int e = e0 + t + k * 256;
    if (e < ETOT) {
      int s, d;
      if (e < EE) { s = ei[e]; d = ei[EE + e]; } else { s = d = e - EE; }
      int b = d >> 8;
      int idx = gbase[b] + atomicAdd(&cnt[b], 1);
      if (idx < CAP)
        ebuf[(size_t)b * CAP + idx] = (unsigned int)s | ((unsigned int)(d & 255) << 16);
    }
  }
}

// ---------------------------------------------------------------------------
// Pass 2: per 256-dst bucket -- local histogram, scan (writes rs), rank
// scatter in LDS, coalesced perm16. Bucket prefix recomputed per block.
// ---------------------------------------------------------------------------
__global__ __launch_bounds__(256) void k_p2(const unsigned int* __restrict__ ebuf,
                                            const int* __restrict__ bcnt,
                                            int* __restrict__ rs,
                                            unsigned short* __restrict__ perm16) {
  __shared__ int sb[256];
  __shared__ int loc[256];
  __shared__ int cnt[256];
  __shared__ unsigned short out16[CAP];
  __shared__ int basesh;
  int b = blockIdx.x, t = threadIdx.x;

  // exclusive prefix over bcnt[0..NBK)
  int v = (t < NBK) ? bcnt[t] : 0;
  sb[t] = v;
  __syncthreads();
  for (int off = 1; off < 256; off <<= 1) {
    int u = (t >= off) ? sb[t - off] : 0;
    __syncthreads();
    sb[t] += u;
    __syncthreads();
  }
  if (t == b) basesh = sb[t] - v;
  cnt[t] = 0;
  __syncthreads();

  int base = basesh;
  int m = min(bcnt[b], CAP);
  int d0 = b * 256;
  const unsigned int* rec = ebuf + (size_t)b * CAP;
  for (int i = t; i < m; i += 256) atomicAdd(&cnt[rec[i] >> 16], 1);
  __syncthreads();

  int c = cnt[t];
  sb[t] = c;
  __syncthreads();
  for (int off = 1; off < 256; off <<= 1) {
    int u = (t >= off) ? sb[t - off] : 0;
    __syncthreads();
    sb[t] += u;
    __syncthreads();
  }
  int ex = sb[t] - c;
  loc[t] = ex;
  int gi = d0 + t;
  if (gi < NN) rs[gi] = base + ex;
  if (b == NBK - 1 && t == 0) rs[NN] = base + m;
  cnt[t] = 0;
  __syncthreads();

  for (int i = t; i < m; i += 256) {
    unsigned int r = rec[i];
    int dl = r >> 16;
    int rk = atomicAdd(&cnt[dl], 1);
    out16[loc[dl] + rk] = (unsigned short)(r & 0xffffu);
  }
  __syncthreads();
  for (int i = t; i < m; i += 256) perm16[base + i] = out16[i];
}

// ---------------------------------------------------------------------------
// Fused aggregation + GEMM. Block = 4 waves, 32 dst rows.
// Phase A: per wave, 8 nodes -> z rows (f32x2 pk-FMA accum) into swizzled LDS.
// Phase B: [32x512](fp16 LDS) x [512x128](Bt, L2) -> out fp32 via MFMA.
// ---------------------------------------------------------------------------
__global__ __launch_bounds__(256) void k_fused(const float* __restrict__ a_s,
                                               const float* __restrict__ a_d,
                                               const unsigned int* __restrict__ xh,
                                               const int* __restrict__ rs,
                                               const unsigned short* __restrict__ perm16,
                                               const unsigned short* __restrict__ Bt,
                                               float* __restrict__ out) {
  __shared__ u32x4 Zl[TM * 64];           // 32 KB, chunk-swizzled per row
  __shared__ float4 w_s[4][MAXD];
  __shared__ unsigned short sn_s[4][MAXD];
  unsigned int* Zw = (unsigned int*)Zl;
  int wave = threadIdx.x >> 6, lane = threadIdx.x & 63;
  int m0 = blockIdx.x * TM;

#pragma unroll 1
  for (int i = 0; i < 8; ++i) {
    int r = wave * 8 + i;
    int n = m0 + r;
    bool valid = (n < NN);
    int s = 0, deg = 0;
    float4 ad = make_float4(0.f, 0.f, 0.f, 0.f);
    if (valid) {
      s = rs[n];
      deg = rs[n + 1] - s;
      ad = *(const float4*)(a_d + n * 4);
    }
    bool fast = (deg <= MAXD);
    float t0 = 0.f, t1 = 0.f, t2 = 0.f, t3 = 0.f;
    if (fast) {
      for (int j = lane; j < deg; j += 64) {
        int sn = perm16[s + j];
        sn_s[wave][j] = (unsigned short)sn;
        float4 as = *(const float4*)(a_s + sn * 4);
        float e0 = __expf(lrelu(as.x + ad.x));
        float e1 = __expf(lrelu(as.y + ad.y));
        float e2 = __expf(lrelu(as.z + ad.z));
        float e3 = __expf(lrelu(as.w + ad.w));
        w_s[wave][j] = make_float4(e0, e1, e2, e3);
        t0 += e0; t1 += e1; t2 += e2; t3 += e3;
      }
    } else {
      for (int j = lane; j < deg; j += 64) {
        int sn = perm16[s + j];
        float4 as = *(const float4*)(a_s + sn * 4);
        t0 += __expf(lrelu(as.x + ad.x)); t1 += __expf(lrelu(as.y + ad.y));
        t2 += __expf(lrelu(as.z + ad.z)); t3 += __expf(lrelu(as.w + ad.w));
      }
    }
#pragma unroll
    for (int off = 32; off; off >>= 1) {
      t0 += __shfl_xor(t0, off); t1 += __shfl_xor(t1, off);
      t2 += __shfl_xor(t2, off); t3 += __shfl_xor(t3, off);
    }
    float sc0 = 0.25f / (t0 + 1e-16f), sc1 = 0.25f / (t1 + 1e-16f);
    float sc2 = 0.25f / (t2 + 1e-16f), sc3 = 0.25f / (t3 + 1e-16f);
    __syncthreads();  // uniform; makes w_s/sn_s visible across lanes

    f32x2 za0 = {0.f, 0.f}, za1 = {0.f, 0.f}, za2 = {0.f, 0.f}, za3 = {0.f, 0.f};
    if (fast) {
      int j = 0;
      for (; j + 4 <= deg; j += 4) {
        int s0_ = sn_s[wave][j],     s1_ = sn_s[wave][j + 1];
        int s2_ = sn_s[wave][j + 2], s3_ = sn_s[wave][j + 3];
        float4 w0 = w_s[wave][j],     w1 = w_s[wave][j + 1];
        float4 w2 = w_s[wave][j + 2], w3 = w_s[wave][j + 3];
        unsigned int u0 = xh[s0_ * 64 + lane];
        unsigned int u1 = xh[s1_ * 64 + lane];
        unsigned int u2 = xh[s2_ * 64 + lane];
        unsigned int u3 = xh[s3_ * 64 + lane];
        f16x2 p0 = __builtin_bit_cast(f16x2, u0);
        f16x2 p1 = __builtin_bit_cast(f16x2, u1);
        f16x2 p2 = __builtin_bit_cast(f16x2, u2);
        f16x2 p3 = __builtin_bit_cast(f16x2, u3);
        f32x2 x0 = {(float)p0[0], (float)p0[1]};
        f32x2 x1 = {(float)p1[0], (float)p1[1]};
        f32x2 x2 = {(float)p2[0], (float)p2[1]};
        f32x2 x3 = {(float)p3[0], (float)p3[1]};
        za0 += w0.x * x0; za1 += w0.y * x0; za2 += w0.z * x0; za3 += w0.w * x0;
        za0 += w1.x * x1; za1 += w1.y * x1; za2 += w1.z * x1; za3 += w1.w * x1;
        za0 += w2.x * x2; za1 += w2.y * x2; za2 += w2.z * x2; za3 += w2.w * x2;
        za0 += w3.x * x3; za1 += w3.y * x3; za2 += w3.z * x3; za3 += w3.w * x3;
      }
      for (; j < deg; ++j) {
        int sa = sn_s[wave][j];
        float4 w = w_s[wave][j];
        unsigned int u = xh[sa * 64 + lane];
        f16x2 p = __builtin_bit_cast(f16x2, u);
        f32x2 xv = {(float)p[0], (float)p[1]};
        za0 += w.x * xv; za1 += w.y * xv; za2 += w.z * xv; za3 += w.w * xv;
      }
    } else {
      for (int j = 0; j < deg; ++j) {
        int sn = perm16[s + j];
        float4 as = *(const float4*)(a_s + sn * 4);
        float w0 = __expf(lrelu(as.x + ad.x));
        float w1 = __expf(lrelu(as.y + ad.y));
        float w2 = __expf(lrelu(as.z + ad.z));
        float w3 = __expf(lrelu(as.w + ad.w));
        unsigned int u = xh[sn * 64 + lane];
        f16x2 p = __builtin_bit_cast(f16x2, u);
        f32x2 xv = {(float)p[0], (float)p[1]};
        za0 += w0 * xv; za1 += w1 * xv; za2 += w2 * xv; za3 += w3 * xv;
      }
    }

    unsigned int pk0 = pack2(za0[0] * sc0, za0[1] * sc0);
    unsigned int pk1 = pack2(za1[0] * sc1, za1[1] * sc1);
    unsigned int pk2 = pack2(za2[0] * sc2, za2[1] * sc2);
    unsigned int pk3 = pack2(za3[0] * sc3, za3[1] * sc3);
    if (!valid) { pk0 = 0u; pk1 = 0u; pk2 = 0u; pk3 = 0u; }
    int rb = r & 7;
    int ct = lane >> 2, sub = lane & 3;
    Zw[r * 256 + (((0 * 16 + ct) ^ rb) << 2) + sub] = pk0;
    Zw[r * 256 + (((1 * 16 + ct) ^ rb) << 2) + sub] = pk1;
    Zw[r * 256 + (((2 * 16 + ct) ^ rb) << 2) + sub] = pk2;
    Zw[r * 256 + (((3 * 16 + ct) ^ rb) << 2) + sub] = pk3;
  }
  __syncthreads();

  // ---- Phase B: GEMM [TM x 512] x [512 x 128] -> out
  int lr = lane & 15, lk = lane >> 4;
  int n0w = wave * 32;
  const u32x4* Bv = (const u32x4*)Bt;
  f32x4 acc[2][2];
#pragma unroll
  for (int mi = 0; mi < 2; ++mi)
#pragma unroll
    for (int ni = 0; ni < 2; ++ni) acc[mi][ni] = (f32x4){0.f, 0.f, 0.f, 0.f};

#pragma unroll
  for (int kk = 0; kk < 16; ++kk) {
    f16x8 af[2], bf[2];
#pragma unroll
    for (int mi = 0; mi < 2; ++mi) {
      int r2 = mi * 16 + lr;
      af[mi] = __builtin_bit_cast(f16x8, Zl[r2 * 64 + ((kk * 4 + lk) ^ (r2 & 7))]);
    }
#pragma unroll
    for (int ni = 0; ni < 2; ++ni) {
      int cix = n0w + ni * 16 + lr;
      bf[ni] = __builtin_bit_cast(f16x8, Bv[cix * 64 + kk * 4 + lk]);
    }
#pragma unroll
    for (int mi = 0; mi < 2; ++mi)
#pragma unroll
      for (int ni = 0; ni < 2; ++ni)
        acc[mi][ni] = __builtin_amdgcn_mfma_f32_16x16x32_f16(af[mi], bf[ni], acc[mi][ni], 0, 0, 0);
  }

  int cr = lk * 4;
#pragma unroll
  for (int mi = 0; mi < 2; ++mi) {
#pragma unroll
    for (int j2 = 0; j2 < 4; ++j2) {
      int row = m0 + mi * 16 + cr + j2;
      if (row < NN) {
#pragma unroll
        for (int ni = 0; ni < 2; ++ni) {
          int col = n0w + ni * 16 + lr;
          out[row * 128 + col] = acc[mi][ni][j2];
        }
      }
    }
  }
}

// ---------------------------------------------------------------------------
extern "C" void kernel_launch(void* const* d_in, const int* in_sizes, int n_in,
                              void* d_out, int out_size, void* d_ws, size_t ws_size,
                              hipStream_t stream) {
  const float* x = (const float*)d_in[0];
  const int* ei = (const int*)d_in[1];
  const float* W = (const float*)d_in[2];
  const float* att_s = (const float*)d_in[3];
  const float* att_d = (const float*)d_in[4];
  float* out = (float*)d_out;
  char* ws = (char*)d_ws;

  unsigned int* xh = (unsigned int*)(ws + 0);                 // 12,800,000 B
  unsigned int* ebuf = (unsigned int*)(ws + 12800000);        //  4,816,896 B
  unsigned short* Bt = (unsigned short*)(ws + 17616896);      //    131,072 B
  float* WaS = (float*)(ws + 17747968);                       //      2,048 B
  float* WaD = (float*)(ws + 17750016);                       //      2,048 B
  float* a_s = (float*)(ws + 17752064);                       //    800,000 B
  float* a_d = (float*)(ws + 18552064);                       //    800,000 B
  int* rs = (int*)(ws + 19352064);                            //    200,192 B
  int* bcnt = (int*)(ws + 19552256);                          //      1,024 B
  unsigned short* perm16 = (unsigned short*)(ws + 19553280);  //  1,700,000 B

  k_prep<<<256, 256, 0, stream>>>(W, att_s, att_d, Bt, WaS, WaD, bcnt);
  k_xcast_p1<<<(NN + 127) / 128, 256, 0, stream>>>(x, WaS, WaD, ei, xh, a_s, a_d, bcnt, ebuf);
  k_p2<<<NBK, 256, 0, stream>>>(ebuf, bcnt, rs, perm16);
  k_fused<<<(NN + TM - 1) / TM, 256, 0, stream>>>(a_s, a_d, xh, rs, perm16, Bt, out);
}

// Round 7
// 145.506 us; speedup vs baseline: 1.0751x; 1.0751x over previous
//
#include <hip/hip_runtime.h>

#define NN 50000
#define EE 800000
#define ETOT (EE + NN)
#define MAXD 96      // max degree on fast path (Poisson(16)+1 -> max ~60)
#define NBK 196      // dst buckets of 256 nodes
#define CAP 6144     // records per bucket slot (mean 4352, +28 sigma)
#define CHX 2304     // edges per xcast block (9*256); 391 blocks cover ETOT
#define TM 16        // dst rows per fused block (4 per wave)

typedef _Float16 f16x8 __attribute__((ext_vector_type(8)));
typedef _Float16 f16x2 __attribute__((ext_vector_type(2)));
typedef float f32x4 __attribute__((ext_vector_type(4)));
typedef float f32x2 __attribute__((ext_vector_type(2)));
typedef unsigned int u32x4 __attribute__((ext_vector_type(4)));

__device__ __forceinline__ float lrelu(float v) { return v > 0.f ? v : 0.2f * v; }
__device__ __forceinline__ unsigned int pack2(float a, float b) {
  unsigned short lo = __builtin_bit_cast(unsigned short, (_Float16)a);
  unsigned short hi = __builtin_bit_cast(unsigned short, (_Float16)b);
  return (unsigned int)lo | ((unsigned int)hi << 16);
}

// ---------------------------------------------------------------------------
// Prep: Bt[col][k] fp16 (k = h*128+c), folded attention WaS/WaD, zero bcnt.
// ---------------------------------------------------------------------------
__global__ void k_prep(const float* __restrict__ W,
                       const float* __restrict__ att_s,
                       const float* __restrict__ att_d,
                       unsigned short* __restrict__ Bt,
                       float* __restrict__ WaS, float* __restrict__ WaD,
                       int* __restrict__ bcnt) {
  int gid = blockIdx.x * blockDim.x + threadIdx.x;
  if (gid < NBK) bcnt[gid] = 0;
  if (gid < 128 * 512) {
    int col = gid >> 9, k = gid & 511;
    float v = W[(k & 127) * 512 + (k >> 7) * 128 + col];
    _Float16 hv = (_Float16)v;
    Bt[col * 512 + k] = __builtin_bit_cast(unsigned short, hv);
  }
  if (gid < 512) {
    int k = gid >> 2, h = gid & 3;
    const float* wrow = W + k * 512 + h * 128;
    const float* as = att_s + h * 128;
    const float* ad = att_d + h * 128;
    float ss = 0.f, sd = 0.f;
    for (int c = 0; c < 128; ++c) { float w = wrow[c]; ss += w * as[c]; sd += w * ad[c]; }
    WaS[k * 4 + h] = ss;
    WaD[k * 4 + h] = sd;
  }
}

// ---------------------------------------------------------------------------
// Fused: x->fp16 xh + a_s/a_d (LDS-staged, 2 thr/node)  AND  pass-1 coarse
// binning of edge records (src | d_local<<16) into 196 bucket slots.
// ---------------------------------------------------------------------------
__global__ __launch_bounds__(256) void k_xcast_p1(const float* __restrict__ x,
                                                  const float* __restrict__ WaS,
                                                  const float* __restrict__ WaD,
                                                  const int* __restrict__ ei,
                                                  unsigned int* __restrict__ xh,
                                                  float* __restrict__ a_s,
                                                  float* __restrict__ a_d,
                                                  int* __restrict__ bcnt,
                                                  unsigned int* __restrict__ ebuf) {
  __shared__ unsigned long long D[128][33];
  __shared__ float4 wsl[128];
  __shared__ float4 wdl[128];
  __shared__ int cnt[NBK];
  __shared__ int gbase[NBK];
  int t = threadIdx.x;
  int nb = blockIdx.x * 128;
  if (t < 128) wsl[t] = ((const float4*)WaS)[t];
  else wdl[t - 128] = ((const float4*)WaD)[t - 128];
  for (int i = t; i < NBK; i += 256) cnt[i] = 0;

#pragma unroll
  for (int i = 0; i < 16; ++i) {
    int idx = t + i * 256;
    int n = idx >> 5, c4 = idx & 31;
    int gn = nb + n;
    float4 v = make_float4(0.f, 0.f, 0.f, 0.f);
    if (gn < NN) v = ((const float4*)x)[(size_t)gn * 32 + c4];
    unsigned int lo = pack2(v.x, v.y);
    unsigned int hi = pack2(v.z, v.w);
    if (gn < NN) ((uint2*)xh)[(size_t)gn * 32 + c4] = make_uint2(lo, hi);
    D[n][c4] = (unsigned long long)lo | ((unsigned long long)hi << 32);
  }
  __syncthreads();

  {
    int n = t >> 1, half = t & 1;
    float s0 = 0.f, s1 = 0.f, s2 = 0.f, s3 = 0.f;
    float d0 = 0.f, d1 = 0.f, d2 = 0.f, d3 = 0.f;
#pragma unroll
    for (int p = 0; p < 16; ++p) {
      int c4 = 2 * p + half;
      unsigned long long q = D[n][c4];
      f16x2 lo2 = __builtin_bit_cast(f16x2, (unsigned int)q);
      f16x2 hi2 = __builtin_bit_cast(f16x2, (unsigned int)(q >> 32));
      float f0 = (float)lo2[0], f1 = (float)lo2[1];
      float f2 = (float)hi2[0], f3 = (float)hi2[1];
      int c = c4 * 4;
      float4 w0 = wsl[c], w1 = wsl[c + 1], w2 = wsl[c + 2], w3 = wsl[c + 3];
      s0 += f0 * w0.x + f1 * w1.x + f2 * w2.x + f3 * w3.x;
      s1 += f0 * w0.y + f1 * w1.y + f2 * w2.y + f3 * w3.y;
      s2 += f0 * w0.z + f1 * w1.z + f2 * w2.z + f3 * w3.z;
      s3 += f0 * w0.w + f1 * w1.w + f2 * w2.w + f3 * w3.w;
      float4 v0 = wdl[c], v1 = wdl[c + 1], v2 = wdl[c + 2], v3 = wdl[c + 3];
      d0 += f0 * v0.x + f1 * v1.x + f2 * v2.x + f3 * v3.x;
      d1 += f0 * v0.y + f1 * v1.y + f2 * v2.y + f3 * v3.y;
      d2 += f0 * v0.z + f1 * v1.z + f2 * v2.z + f3 * v3.z;
      d3 += f0 * v0.w + f1 * v1.w + f2 * v2.w + f3 * v3.w;
    }
    s0 += __shfl_xor(s0, 1); s1 += __shfl_xor(s1, 1);
    s2 += __shfl_xor(s2, 1); s3 += __shfl_xor(s3, 1);
    d0 += __shfl_xor(d0, 1); d1 += __shfl_xor(d1, 1);
    d2 += __shfl_xor(d2, 1); d3 += __shfl_xor(d3, 1);
    int gn = nb + n;
    if (half == 0 && gn < NN) {
      *(float4*)(a_s + gn * 4) = make_float4(s0, s1, s2, s3);
      *(float4*)(a_d + gn * 4) = make_float4(d0, d1, d2, d3);
    }
  }

  // ---- pass 1: coarse dst-binning (cnt[] zeroed before first barrier)
  int e0 = blockIdx.x * CHX;
#pragma unroll
  for (int k = 0; k < CHX / 256; ++k) {
    int e = e0 + t + k * 256;
    if (e < ETOT) {
      int d = (e < EE) ? ei[EE + e] : (e - EE);
      atomicAdd(&cnt[d >> 8], 1);
    }
  }
  __syncthreads();
  for (int i = t; i < NBK; i += 256) {
    gbase[i] = (cnt[i] > 0) ? atomicAdd(&bcnt[i], cnt[i]) : 0;
    cnt[i] = 0;
  }
  __syncthreads();
#pragma unroll
  for (int k = 0; k < CHX / 256; ++k) {
    int e = e0 + t + k * 256;
    if (e < ETOT) {
      int s, d;
      if (e < EE) { s = ei[e]; d = ei[EE + e]; } else { s = d = e - EE; }
      int b = d >> 8;
      int idx = gbase[b] + atomicAdd(&cnt[b], 1);
      if (idx < CAP)
        ebuf[(size_t)b * CAP + idx] = (unsigned int)s | ((unsigned int)(d & 255) << 16);
    }
  }
}

// ---------------------------------------------------------------------------
// Pass 2: per 256-dst bucket -- local histogram, scan (writes rs), rank
// scatter in LDS, coalesced perm16. Bucket prefix recomputed per block.
// ---------------------------------------------------------------------------
__global__ __launch_bounds__(256) void k_p2(const unsigned int* __restrict__ ebuf,
                                            const int* __restrict__ bcnt,
                                            int* __restrict__ rs,
                                            unsigned short* __restrict__ perm16) {
  __shared__ int sb[256];
  __shared__ int loc[256];
  __shared__ int cnt[256];
  __shared__ unsigned short out16[CAP];
  __shared__ int basesh;
  int b = blockIdx.x, t = threadIdx.x;

  int v = (t < NBK) ? bcnt[t] : 0;
  sb[t] = v;
  __syncthreads();
  for (int off = 1; off < 256; off <<= 1) {
    int u = (t >= off) ? sb[t - off] : 0;
    __syncthreads();
    sb[t] += u;
    __syncthreads();
  }
  if (t == b) basesh = sb[t] - v;
  cnt[t] = 0;
  __syncthreads();

  int base = basesh;
  int m = min(bcnt[b], CAP);
  int d0 = b * 256;
  const unsigned int* rec = ebuf + (size_t)b * CAP;
  for (int i = t; i < m; i += 256) atomicAdd(&cnt[rec[i] >> 16], 1);
  __syncthreads();

  int c = cnt[t];
  sb[t] = c;
  __syncthreads();
  for (int off = 1; off < 256; off <<= 1) {
    int u = (t >= off) ? sb[t - off] : 0;
    __syncthreads();
    sb[t] += u;
    __syncthreads();
  }
  int ex = sb[t] - c;
  loc[t] = ex;
  int gi = d0 + t;
  if (gi < NN) rs[gi] = base + ex;
  if (b == NBK - 1 && t == 0) rs[NN] = base + m;
  cnt[t] = 0;
  __syncthreads();

  for (int i = t; i < m; i += 256) {
    unsigned int r = rec[i];
    int dl = r >> 16;
    int rk = atomicAdd(&cnt[dl], 1);
    out16[loc[dl] + rk] = (unsigned short)(r & 0xffffu);
  }
  __syncthreads();
  for (int i = t; i < m; i += 256) perm16[base + i] = out16[i];
}

// ---------------------------------------------------------------------------
// Fused aggregation + GEMM. Block = 4 waves, 16 dst rows (4 per wave).
// Phase A: per wave, 4 nodes -> z rows into swizzled LDS. NO block barriers
// inside the loop (w_s/sn_s are per-wave; intra-wave LDS is ordered).
// Phase B: [16x512](fp16 LDS) x [512x128](Bt, L2) -> out fp32 via MFMA.
// ---------------------------------------------------------------------------
__global__ __launch_bounds__(256) void k_fused(const float* __restrict__ a_s,
                                               const float* __restrict__ a_d,
                                               const unsigned int* __restrict__ xh,
                                               const int* __restrict__ rs,
                                               const unsigned short* __restrict__ perm16,
                                               const unsigned short* __restrict__ Bt,
                                               float* __restrict__ out) {
  __shared__ u32x4 Zl[TM * 64];           // 16 KB, chunk-swizzled per row
  __shared__ float4 w_s[4][MAXD];
  __shared__ unsigned short sn_s[4][MAXD];
  unsigned int* Zw = (unsigned int*)Zl;
  int wave = threadIdx.x >> 6, lane = threadIdx.x & 63;
  int m0 = blockIdx.x * TM;

#pragma unroll 1
  for (int i = 0; i < 4; ++i) {
    int r = wave * 4 + i;
    int n = m0 + r;
    bool valid = (n < NN);
    int s = 0, deg = 0;
    float4 ad = make_float4(0.f, 0.f, 0.f, 0.f);
    if (valid) {
      s = rs[n];
      deg = rs[n + 1] - s;
      ad = *(const float4*)(a_d + n * 4);
    }
    bool fast = (deg <= MAXD);
    float t0 = 0.f, t1 = 0.f, t2 = 0.f, t3 = 0.f;
    if (fast) {
      for (int j = lane; j < deg; j += 64) {
        int sn = perm16[s + j];
        sn_s[wave][j] = (unsigned short)sn;
        float4 as = *(const float4*)(a_s + sn * 4);
        float e0 = __expf(lrelu(as.x + ad.x));
        float e1 = __expf(lrelu(as.y + ad.y));
        float e2 = __expf(lrelu(as.z + ad.z));
        float e3 = __expf(lrelu(as.w + ad.w));
        w_s[wave][j] = make_float4(e0, e1, e2, e3);
        t0 += e0; t1 += e1; t2 += e2; t3 += e3;
      }
    } else {
      for (int j = lane; j < deg; j += 64) {
        int sn = perm16[s + j];
        float4 as = *(const float4*)(a_s + sn * 4);
        t0 += __expf(lrelu(as.x + ad.x)); t1 += __expf(lrelu(as.y + ad.y));
        t2 += __expf(lrelu(as.z + ad.z)); t3 += __expf(lrelu(as.w + ad.w));
      }
    }
#pragma unroll
    for (int off = 32; off; off >>= 1) {
      t0 += __shfl_xor(t0, off); t1 += __shfl_xor(t1, off);
      t2 += __shfl_xor(t2, off); t3 += __shfl_xor(t3, off);
    }
    float sc0 = 0.25f / (t0 + 1e-16f), sc1 = 0.25f / (t1 + 1e-16f);
    float sc2 = 0.25f / (t2 + 1e-16f), sc3 = 0.25f / (t3 + 1e-16f);
    __builtin_amdgcn_wave_barrier();  // scheduling fence only (intra-wave LDS)

    f32x2 za0 = {0.f, 0.f}, za1 = {0.f, 0.f}, za2 = {0.f, 0.f}, za3 = {0.f, 0.f};
    if (fast) {
      int j = 0;
      for (; j + 8 <= deg; j += 8) {
        unsigned int u[8];
        float4 w[8];
#pragma unroll
        for (int k = 0; k < 8; ++k) {
          int sa = sn_s[wave][j + k];
          u[k] = xh[sa * 64 + lane];
          w[k] = w_s[wave][j + k];
        }
#pragma unroll
        for (int k = 0; k < 8; ++k) {
          f16x2 p = __builtin_bit_cast(f16x2, u[k]);
          f32x2 xv = {(float)p[0], (float)p[1]};
          za0 += w[k].x * xv; za1 += w[k].y * xv;
          za2 += w[k].z * xv; za3 += w[k].w * xv;
        }
      }
      if (j + 4 <= deg) {
        unsigned int u[4];
        float4 w[4];
#pragma unroll
        for (int k = 0; k < 4; ++k) {
          int sa = sn_s[wave][j + k];
          u[k] = xh[sa * 64 + lane];
          w[k] = w_s[wave][j + k];
        }
#pragma unroll
        for (int k = 0; k < 4; ++k) {
          f16x2 p = __builtin_bit_cast(f16x2, u[k]);
          f32x2 xv = {(float)p[0], (float)p[1]};
          za0 += w[k].x * xv; za1 += w[k].y * xv;
          za2 += w[k].z * xv; za3 += w[k].w * xv;
        }
        j += 4;
      }
      for (; j < deg; ++j) {
        int sa = sn_s[wave][j];
        float4 w = w_s[wave][j];
        unsigned int u = xh[sa * 64 + lane];
        f16x2 p = __builtin_bit_cast(f16x2, u);
        f32x2 xv = {(float)p[0], (float)p[1]};
        za0 += w.x * xv; za1 += w.y * xv; za2 += w.z * xv; za3 += w.w * xv;
      }
    } else {
      for (int j = 0; j < deg; ++j) {
        int sn = perm16[s + j];
        float4 as = *(const float4*)(a_s + sn * 4);
        float w0 = __expf(lrelu(as.x + ad.x));
        float w1 = __expf(lrelu(as.y + ad.y));
        float w2 = __expf(lrelu(as.z + ad.z));
        float w3 = __expf(lrelu(as.w + ad.w));
        unsigned int u = xh[sn * 64 + lane];
        f16x2 p = __builtin_bit_cast(f16x2, u);
        f32x2 xv = {(float)p[0], (float)p[1]};
        za0 += w0 * xv; za1 += w1 * xv; za2 += w2 * xv; za3 += w3 * xv;
      }
    }

    unsigned int pk0 = pack2(za0[0] * sc0, za0[1] * sc0);
    unsigned int pk1 = pack2(za1[0] * sc1, za1[1] * sc1);
    unsigned int pk2 = pack2(za2[0] * sc2, za2[1] * sc2);
    unsigned int pk3 = pack2(za3[0] * sc3, za3[1] * sc3);
    if (!valid) { pk0 = 0u; pk1 = 0u; pk2 = 0u; pk3 = 0u; }
    int rb = r & 7;
    int ct = lane >> 2, sub = lane & 3;
    Zw[r * 256 + (((0 * 16 + ct) ^ rb) << 2) + sub] = pk0;
    Zw[r * 256 + (((1 * 16 + ct) ^ rb) << 2) + sub] = pk1;
    Zw[r * 256 + (((2 * 16 + ct) ^ rb) << 2) + sub] = pk2;
    Zw[r * 256 + (((3 * 16 + ct) ^ rb) << 2) + sub] = pk3;
  }
  __syncthreads();  // ONE barrier: Z tile complete

  // ---- Phase B: GEMM [TM x 512] x [512 x 128] -> out (wave: 16 x 32 cols)
  int lr = lane & 15, lk = lane >> 4;
  int n0w = wave * 32;
  const u32x4* Bv = (const u32x4*)Bt;
  f32x4 acc[2];
#pragma unroll
  for (int ni = 0; ni < 2; ++ni) acc[ni] = (f32x4){0.f, 0.f, 0.f, 0.f};

#pragma unroll
  for (int kk = 0; kk < 16; ++kk) {
    f16x8 af = __builtin_bit_cast(f16x8, Zl[lr * 64 + ((kk * 4 + lk) ^ (lr & 7))]);
#pragma unroll
    for (int ni = 0; ni < 2; ++ni) {
      int cix = n0w + ni * 16 + lr;
      f16x8 bf = __builtin_bit_cast(f16x8, Bv[cix * 64 + kk * 4 + lk]);
      acc[ni] = __builtin_amdgcn_mfma_f32_16x16x32_f16(af, bf, acc[ni], 0, 0, 0);
    }
  }

  int cr = lk * 4;
#pragma unroll
  for (int j2 = 0; j2 < 4; ++j2) {
    int row = m0 + cr + j2;
    if (row < NN) {
#pragma unroll
      for (int ni = 0; ni < 2; ++ni) {
        int col = n0w + ni * 16 + lr;
        out[row * 128 + col] = acc[ni][j2];
      }
    }
  }
}

// ---------------------------------------------------------------------------
extern "C" void kernel_launch(void* const* d_in, const int* in_sizes, int n_in,
                              void* d_out, int out_size, void* d_ws, size_t ws_size,
                              hipStream_t stream) {
  const float* x = (const float*)d_in[0];
  const int* ei = (const int*)d_in[1];
  const float* W = (const float*)d_in[2];
  const float* att_s = (const float*)d_in[3];
  const float* att_d = (const float*)d_in[4];
  float* out = (float*)d_out;
  char* ws = (char*)d_ws;

  unsigned int* xh = (unsigned int*)(ws + 0);                 // 12,800,000 B
  unsigned int* ebuf = (unsigned int*)(ws + 12800000);        //  4,816,896 B
  unsigned short* Bt = (unsigned short*)(ws + 17616896);      //    131,072 B
  float* WaS = (float*)(ws + 17747968);                       //      2,048 B
  float* WaD = (float*)(ws + 17750016);                       //      2,048 B
  float* a_s = (float*)(ws + 17752064);                       //    800,000 B
  float* a_d = (float*)(ws + 18552064);                       //    800,000 B
  int* rs = (int*)(ws + 19352064);                            //    200,192 B
  int* bcnt = (int*)(ws + 19552256);                          //      1,024 B
  unsigned short* perm16 = (unsigned short*)(ws + 19553280);  //  1,700,000 B

  k_prep<<<256, 256, 0, stream>>>(W, att_s, att_d, Bt, WaS, WaD, bcnt);
  k_xcast_p1<<<(NN + 127) / 128, 256, 0, stream>>>(x, WaS, WaD, ei, xh, a_s, a_d, bcnt, ebuf);
  k_p2<<<NBK, 256, 0, stream>>>(ebuf, bcnt, rs, perm16);
  k_fused<<<(NN + TM - 1) / TM, 256, 0, stream>>>(a_s, a_d, xh, rs, perm16, Bt, out);
}

// Round 8
// 138.973 us; speedup vs baseline: 1.1256x; 1.0470x over previous
//
#include <hip/hip_runtime.h>

#define NN 50000
#define EE 800000
#define ETOT (EE + NN)
#define MAXD 64      // max degree on fast path (Poisson(16)+1 -> max ~45)
#define NBK 196      // dst buckets of 256 nodes
#define CAP 6144     // records per bucket slot (mean 4352, +28 sigma)
#define CHX 2304     // edges per xcast block (9*256); 391 blocks cover ETOT
#define TM 16        // dst rows per fused block (1 per wave, 16 waves)

typedef _Float16 f16x8 __attribute__((ext_vector_type(8)));
typedef _Float16 f16x2 __attribute__((ext_vector_type(2)));
typedef float f32x4 __attribute__((ext_vector_type(4)));
typedef float f32x2 __attribute__((ext_vector_type(2)));
typedef unsigned int u32x4 __attribute__((ext_vector_type(4)));

__device__ __forceinline__ float lrelu(float v) { return v > 0.f ? v : 0.2f * v; }
__device__ __forceinline__ unsigned int pack2(float a, float b) {
  unsigned short lo = __builtin_bit_cast(unsigned short, (_Float16)a);
  unsigned short hi = __builtin_bit_cast(unsigned short, (_Float16)b);
  return (unsigned int)lo | ((unsigned int)hi << 16);
}

// ---------------------------------------------------------------------------
// Prep: Bt[col][k] fp16 (k = h*128+c), folded attention WaS/WaD, zero bcnt.
// ---------------------------------------------------------------------------
__global__ void k_prep(const float* __restrict__ W,
                       const float* __restrict__ att_s,
                       const float* __restrict__ att_d,
                       unsigned short* __restrict__ Bt,
                       float* __restrict__ WaS, float* __restrict__ WaD,
                       int* __restrict__ bcnt) {
  int gid = blockIdx.x * blockDim.x + threadIdx.x;
  if (gid < NBK) bcnt[gid] = 0;
  if (gid < 128 * 512) {
    int col = gid >> 9, k = gid & 511;
    float v = W[(k & 127) * 512 + (k >> 7) * 128 + col];
    _Float16 hv = (_Float16)v;
    Bt[col * 512 + k] = __builtin_bit_cast(unsigned short, hv);
  }
  if (gid < 512) {
    int k = gid >> 2, h = gid & 3;
    const float* wrow = W + k * 512 + h * 128;
    const float* as = att_s + h * 128;
    const float* ad = att_d + h * 128;
    float ss = 0.f, sd = 0.f;
    for (int c = 0; c < 128; ++c) { float w = wrow[c]; ss += w * as[c]; sd += w * ad[c]; }
    WaS[k * 4 + h] = ss;
    WaD[k * 4 + h] = sd;
  }
}

// ---------------------------------------------------------------------------
// Fused: x->fp16 xh + a_s/a_d (LDS-staged, 2 thr/node)  AND  pass-1 coarse
// binning of edge records (src | d_local<<16) into 196 bucket slots.
// ---------------------------------------------------------------------------
__global__ __launch_bounds__(256) void k_xcast_p1(const float* __restrict__ x,
                                                  const float* __restrict__ WaS,
                                                  const float* __restrict__ WaD,
                                                  const int* __restrict__ ei,
                                                  unsigned int* __restrict__ xh,
                                                  float* __restrict__ a_s,
                                                  float* __restrict__ a_d,
                                                  int* __restrict__ bcnt,
                                                  unsigned int* __restrict__ ebuf) {
  __shared__ unsigned long long D[128][33];
  __shared__ float4 wsl[128];
  __shared__ float4 wdl[128];
  __shared__ int cnt[NBK];
  __shared__ int gbase[NBK];
  int t = threadIdx.x;
  int nb = blockIdx.x * 128;
  if (t < 128) wsl[t] = ((const float4*)WaS)[t];
  else wdl[t - 128] = ((const float4*)WaD)[t - 128];
  for (int i = t; i < NBK; i += 256) cnt[i] = 0;

#pragma unroll
  for (int i = 0; i < 16; ++i) {
    int idx = t + i * 256;
    int n = idx >> 5, c4 = idx & 31;
    int gn = nb + n;
    float4 v = make_float4(0.f, 0.f, 0.f, 0.f);
    if (gn < NN) v = ((const float4*)x)[(size_t)gn * 32 + c4];
    unsigned int lo = pack2(v.x, v.y);
    unsigned int hi = pack2(v.z, v.w);
    if (gn < NN) ((uint2*)xh)[(size_t)gn * 32 + c4] = make_uint2(lo, hi);
    D[n][c4] = (unsigned long long)lo | ((unsigned long long)hi << 32);
  }
  __syncthreads();

  {
    int n = t >> 1, half = t & 1;
    float s0 = 0.f, s1 = 0.f, s2 = 0.f, s3 = 0.f;
    float d0 = 0.f, d1 = 0.f, d2 = 0.f, d3 = 0.f;
#pragma unroll
    for (int p = 0; p < 16; ++p) {
      int c4 = 2 * p + half;
      unsigned long long q = D[n][c4];
      f16x2 lo2 = __builtin_bit_cast(f16x2, (unsigned int)q);
      f16x2 hi2 = __builtin_bit_cast(f16x2, (unsigned int)(q >> 32));
      float f0 = (float)lo2[0], f1 = (float)lo2[1];
      float f2 = (float)hi2[0], f3 = (float)hi2[1];
      int c = c4 * 4;
      float4 w0 = wsl[c], w1 = wsl[c + 1], w2 = wsl[c + 2], w3 = wsl[c + 3];
      s0 += f0 * w0.x + f1 * w1.x + f2 * w2.x + f3 * w3.x;
      s1 += f0 * w0.y + f1 * w1.y + f2 * w2.y + f3 * w3.y;
      s2 += f0 * w0.z + f1 * w1.z + f2 * w2.z + f3 * w3.z;
      s3 += f0 * w0.w + f1 * w1.w + f2 * w2.w + f3 * w3.w;
      float4 v0 = wdl[c], v1 = wdl[c + 1], v2 = wdl[c + 2], v3 = wdl[c + 3];
      d0 += f0 * v0.x + f1 * v1.x + f2 * v2.x + f3 * v3.x;
      d1 += f0 * v0.y + f1 * v1.y + f2 * v2.y + f3 * v3.y;
      d2 += f0 * v0.z + f1 * v1.z + f2 * v2.z + f3 * v3.z;
      d3 += f0 * v0.w + f1 * v1.w + f2 * v2.w + f3 * v3.w;
    }
    s0 += __shfl_xor(s0, 1); s1 += __shfl_xor(s1, 1);
    s2 += __shfl_xor(s2, 1); s3 += __shfl_xor(s3, 1);
    d0 += __shfl_xor(d0, 1); d1 += __shfl_xor(d1, 1);
    d2 += __shfl_xor(d2, 1); d3 += __shfl_xor(d3, 1);
    int gn = nb + n;
    if (half == 0 && gn < NN) {
      *(float4*)(a_s + gn * 4) = make_float4(s0, s1, s2, s3);
      *(float4*)(a_d + gn * 4) = make_float4(d0, d1, d2, d3);
    }
  }

  // ---- pass 1: coarse dst-binning
  int e0 = blockIdx.x * CHX;
#pragma unroll
  for (int k = 0; k < CHX / 256; ++k) {
    int e = e0 + t + k * 256;
    if (e < ETOT) {
      int d = (e < EE) ? ei[EE + e] : (e - EE);
      atomicAdd(&cnt[d >> 8], 1);
    }
  }
  __syncthreads();
  for (int i = t; i < NBK; i += 256) {
    gbase[i] = (cnt[i] > 0) ? atomicAdd(&bcnt[i], cnt[i]) : 0;
    cnt[i] = 0;
  }
  __syncthreads();
#pragma unroll
  for (int k = 0; k < CHX / 256; ++k) {
    int e = e0 + t + k * 256;
    if (e < ETOT) {
      int s, d;
      if (e < EE) { s = ei[e]; d = ei[EE + e]; } else { s = d = e - EE; }
      int b = d >> 8;
      int idx = gbase[b] + atomicAdd(&cnt[b], 1);
      if (idx < CAP)
        ebuf[(size_t)b * CAP + idx] = (unsigned int)s | ((unsigned int)(d & 255) << 16);
    }
  }
}

// ---------------------------------------------------------------------------
// Pass 2: per 256-dst bucket -- local histogram, scan (writes rs), rank
// scatter in LDS, coalesced perm16.
// ---------------------------------------------------------------------------
__global__ __launch_bounds__(256) void k_p2(const unsigned int* __restrict__ ebuf,
                                            const int* __restrict__ bcnt,
                                            int* __restrict__ rs,
                                            unsigned short* __restrict__ perm16) {
  __shared__ int sb[256];
  __shared__ int loc[256];
  __shared__ int cnt[256];
  __shared__ unsigned short out16[CAP];
  __shared__ int basesh;
  int b = blockIdx.x, t = threadIdx.x;

  int v = (t < NBK) ? bcnt[t] : 0;
  sb[t] = v;
  __syncthreads();
  for (int off = 1; off < 256; off <<= 1) {
    int u = (t >= off) ? sb[t - off] : 0;
    __syncthreads();
    sb[t] += u;
    __syncthreads();
  }
  if (t == b) basesh = sb[t] - v;
  cnt[t] = 0;
  __syncthreads();

  int base = basesh;
  int m = min(bcnt[b], CAP);
  int d0 = b * 256;
  const unsigned int* rec = ebuf + (size_t)b * CAP;
  for (int i = t; i < m; i += 256) atomicAdd(&cnt[rec[i] >> 16], 1);
  __syncthreads();

  int c = cnt[t];
  sb[t] = c;
  __syncthreads();
  for (int off = 1; off < 256; off <<= 1) {
    int u = (t >= off) ? sb[t - off] : 0;
    __syncthreads();
    sb[t] += u;
    __syncthreads();
  }
  int ex = sb[t] - c;
  loc[t] = ex;
  int gi = d0 + t;
  if (gi < NN) rs[gi] = base + ex;
  if (b == NBK - 1 && t == 0) rs[NN] = base + m;
  cnt[t] = 0;
  __syncthreads();

  for (int i = t; i < m; i += 256) {
    unsigned int r = rec[i];
    int dl = r >> 16;
    int rk = atomicAdd(&cnt[dl], 1);
    out16[loc[dl] + rk] = (unsigned short)(r & 0xffffu);
  }
  __syncthreads();
  for (int i = t; i < m; i += 256) perm16[base + i] = out16[i];
}

// ---------------------------------------------------------------------------
// Fused aggregation + GEMM. Block = 16 waves (1024 thr), 16 dst rows,
// ONE node per wave (split-aggz concurrency). 2 blocks/CU = 32 waves/CU.
// Phase A: weights (lane-parallel) -> per-wave LDS planes; serial feature
// gather (8-deep ILP) -> swizzled Zl row. One barrier.
// Phase B: waves 0-7 do [16x512]x[512x16] MFMA strips; waves 8-15 exit.
// ---------------------------------------------------------------------------
__global__ __launch_bounds__(1024, 2) void k_fused(const float* __restrict__ a_s,
                                                   const float* __restrict__ a_d,
                                                   const unsigned int* __restrict__ xh,
                                                   const int* __restrict__ rs,
                                                   const unsigned short* __restrict__ perm16,
                                                   const unsigned short* __restrict__ Bt,
                                                   float* __restrict__ out) {
  __shared__ u32x4 Zl[TM * 64];            // 16 KB, chunk-swizzled per row
  __shared__ f32x2 wlo[16][MAXD];          // 8 KB  (e0,e1)
  __shared__ f32x2 whi[16][MAXD];          // 8 KB  (e2,e3)
  __shared__ unsigned short sn_s[16][MAXD];// 2 KB
  unsigned int* Zw = (unsigned int*)Zl;
  int wave = threadIdx.x >> 6, lane = threadIdx.x & 63;
  int m0 = blockIdx.x * TM;
  int n = m0 + wave;  // NN = 3125*16 exactly

  int s = rs[n];
  int deg = rs[n + 1] - s;
  float4 ad = *(const float4*)(a_d + n * 4);
  bool fast = (deg <= MAXD);

  float t0 = 0.f, t1 = 0.f, t2 = 0.f, t3 = 0.f;
  if (fast) {
    if (lane < deg) {
      int sn = perm16[s + lane];
      sn_s[wave][lane] = (unsigned short)sn;
      float4 as = *(const float4*)(a_s + sn * 4);
      float e0 = __expf(lrelu(as.x + ad.x));
      float e1 = __expf(lrelu(as.y + ad.y));
      float e2 = __expf(lrelu(as.z + ad.z));
      float e3 = __expf(lrelu(as.w + ad.w));
      wlo[wave][lane] = (f32x2){e0, e1};
      whi[wave][lane] = (f32x2){e2, e3};
      t0 = e0; t1 = e1; t2 = e2; t3 = e3;
    }
  } else {
    for (int j = lane; j < deg; j += 64) {
      int sn = perm16[s + j];
      float4 as = *(const float4*)(a_s + sn * 4);
      t0 += __expf(lrelu(as.x + ad.x)); t1 += __expf(lrelu(as.y + ad.y));
      t2 += __expf(lrelu(as.z + ad.z)); t3 += __expf(lrelu(as.w + ad.w));
    }
  }
#pragma unroll
  for (int off = 32; off; off >>= 1) {
    t0 += __shfl_xor(t0, off); t1 += __shfl_xor(t1, off);
    t2 += __shfl_xor(t2, off); t3 += __shfl_xor(t3, off);
  }
  float sc0 = 0.25f / (t0 + 1e-16f), sc1 = 0.25f / (t1 + 1e-16f);
  float sc2 = 0.25f / (t2 + 1e-16f), sc3 = 0.25f / (t3 + 1e-16f);
  __builtin_amdgcn_wave_barrier();  // intra-wave LDS ordering fence

  f32x2 za0 = {0.f, 0.f}, za1 = {0.f, 0.f}, za2 = {0.f, 0.f}, za3 = {0.f, 0.f};
  if (fast) {
    int j = 0;
    for (; j + 8 <= deg; j += 8) {
      unsigned int u[8];
#pragma unroll
      for (int k = 0; k < 8; ++k) u[k] = xh[(int)sn_s[wave][j + k] * 64 + lane];
#pragma unroll
      for (int k = 0; k < 8; ++k) {
        f32x2 wl = wlo[wave][j + k];
        f32x2 wh = whi[wave][j + k];
        f16x2 p = __builtin_bit_cast(f16x2, u[k]);
        f32x2 xv = {(float)p[0], (float)p[1]};
        za0 += wl[0] * xv; za1 += wl[1] * xv;
        za2 += wh[0] * xv; za3 += wh[1] * xv;
      }
    }
    if (j + 4 <= deg) {
      unsigned int u[4];
#pragma unroll
      for (int k = 0; k < 4; ++k) u[k] = xh[(int)sn_s[wave][j + k] * 64 + lane];
#pragma unroll
      for (int k = 0; k < 4; ++k) {
        f32x2 wl = wlo[wave][j + k];
        f32x2 wh = whi[wave][j + k];
        f16x2 p = __builtin_bit_cast(f16x2, u[k]);
        f32x2 xv = {(float)p[0], (float)p[1]};
        za0 += wl[0] * xv; za1 += wl[1] * xv;
        za2 += wh[0] * xv; za3 += wh[1] * xv;
      }
      j += 4;
    }
    for (; j < deg; ++j) {
      f32x2 wl = wlo[wave][j];
      f32x2 wh = whi[wave][j];
      unsigned int u = xh[(int)sn_s[wave][j] * 64 + lane];
      f16x2 p = __builtin_bit_cast(f16x2, u);
      f32x2 xv = {(float)p[0], (float)p[1]};
      za0 += wl[0] * xv; za1 += wl[1] * xv;
      za2 += wh[0] * xv; za3 += wh[1] * xv;
    }
  } else {
    for (int j = 0; j < deg; ++j) {
      int sn = perm16[s + j];
      float4 as = *(const float4*)(a_s + sn * 4);
      float w0 = __expf(lrelu(as.x + ad.x));
      float w1 = __expf(lrelu(as.y + ad.y));
      float w2 = __expf(lrelu(as.z + ad.z));
      float w3 = __expf(lrelu(as.w + ad.w));
      unsigned int u = xh[sn * 64 + lane];
      f16x2 p = __builtin_bit_cast(f16x2, u);
      f32x2 xv = {(float)p[0], (float)p[1]};
      za0 += w0 * xv; za1 += w1 * xv; za2 += w2 * xv; za3 += w3 * xv;
    }
  }

  unsigned int pk0 = pack2(za0[0] * sc0, za0[1] * sc0);
  unsigned int pk1 = pack2(za1[0] * sc1, za1[1] * sc1);
  unsigned int pk2 = pack2(za2[0] * sc2, za2[1] * sc2);
  unsigned int pk3 = pack2(za3[0] * sc3, za3[1] * sc3);
  int rb = wave & 7;
  int ct = lane >> 2, sub = lane & 3;
  Zw[wave * 256 + (((0 * 16 + ct) ^ rb) << 2) + sub] = pk0;
  Zw[wave * 256 + (((1 * 16 + ct) ^ rb) << 2) + sub] = pk1;
  Zw[wave * 256 + (((2 * 16 + ct) ^ rb) << 2) + sub] = pk2;
  Zw[wave * 256 + (((3 * 16 + ct) ^ rb) << 2) + sub] = pk3;
  __syncthreads();  // Z tile complete

  if (wave >= 8) return;  // free wave slots for other blocks' phase A

  // ---- Phase B: wave w -> cols [w*16, w*16+16), rows [m0, m0+16)
  int lr = lane & 15, lk = lane >> 4;
  int n0w = wave * 16;
  const u32x4* Bv = (const u32x4*)Bt;
  f32x4 acc = (f32x4){0.f, 0.f, 0.f, 0.f};
#pragma unroll
  for (int kk = 0; kk < 16; ++kk) {
    f16x8 af = __builtin_bit_cast(f16x8, Zl[lr * 64 + ((kk * 4 + lk) ^ (lr & 7))]);
    f16x8 bf = __builtin_bit_cast(f16x8, Bv[(n0w + lr) * 64 + kk * 4 + lk]);
    acc = __builtin_amdgcn_mfma_f32_16x16x32_f16(af, bf, acc, 0, 0, 0);
  }
  int cr = lk * 4;
#pragma unroll
  for (int j2 = 0; j2 < 4; ++j2) {
    out[(m0 + cr + j2) * 128 + n0w + lr] = acc[j2];
  }
}

// ---------------------------------------------------------------------------
extern "C" void kernel_launch(void* const* d_in, const int* in_sizes, int n_in,
                              void* d_out, int out_size, void* d_ws, size_t ws_size,
                              hipStream_t stream) {
  const float* x = (const float*)d_in[0];
  const int* ei = (const int*)d_in[1];
  const float* W = (const float*)d_in[2];
  const float* att_s = (const float*)d_in[3];
  const float* att_d = (const float*)d_in[4];
  float* out = (float*)d_out;
  char* ws = (char*)d_ws;

  unsigned int* xh = (unsigned int*)(ws + 0);                 // 12,800,000 B
  unsigned int* ebuf = (unsigned int*)(ws + 12800000);        //  4,816,896 B
  unsigned short* Bt = (unsigned short*)(ws + 17616896);      //    131,072 B
  float* WaS = (float*)(ws + 17747968);                       //      2,048 B
  float* WaD = (float*)(ws + 17750016);                       //      2,048 B
  float* a_s = (float*)(ws + 17752064);                       //    800,000 B
  float* a_d = (float*)(ws + 18552064);                       //    800,000 B
  int* rs = (int*)(ws + 19352064);                            //    200,192 B
  int* bcnt = (int*)(ws + 19552256);                          //      1,024 B
  unsigned short* perm16 = (unsigned short*)(ws + 19553280);  //  1,700,000 B

  k_prep<<<256, 256, 0, stream>>>(W, att_s, att_d, Bt, WaS, WaD, bcnt);
  k_xcast_p1<<<(NN + 127) / 128, 256, 0, stream>>>(x, WaS, WaD, ei, xh, a_s, a_d, bcnt, ebuf);
  k_p2<<<NBK, 256, 0, stream>>>(ebuf, bcnt, rs, perm16);
  k_fused<<<NN / TM, 1024, 0, stream>>>(a_s, a_d, xh, rs, perm16, Bt, out);
}

// Round 9
// 122.646 us; speedup vs baseline: 1.2754x; 1.1331x over previous
//
#include <hip/hip_runtime.h>

#define NN 50000
#define EE 800000
#define ETOT (EE + NN)
#define MAXD 64      // max degree on fast path (Poisson(16)+1 -> max ~45)
#define NBK 196      // dst buckets of 256 nodes
#define CAP 6144     // records per bucket slot (mean 4352)
#define CHX 2304     // edges per xcast block (9*256); 391 blocks cover ETOT

typedef _Float16 f16x8 __attribute__((ext_vector_type(8)));
typedef _Float16 f16x2 __attribute__((ext_vector_type(2)));
typedef float f32x4 __attribute__((ext_vector_type(4)));
typedef float f32x2 __attribute__((ext_vector_type(2)));
typedef unsigned int u32x4 __attribute__((ext_vector_type(4)));

__device__ __forceinline__ float lrelu(float v) { return v > 0.f ? v : 0.2f * v; }
__device__ __forceinline__ unsigned int pack2(float a, float b) {
  unsigned short lo = __builtin_bit_cast(unsigned short, (_Float16)a);
  unsigned short hi = __builtin_bit_cast(unsigned short, (_Float16)b);
  return (unsigned int)lo | ((unsigned int)hi << 16);
}

// ---------------------------------------------------------------------------
// Prep: Bt[col][k] fp16 (k = h*128+c), folded attention WaS/WaD, zero bcnt.
// ---------------------------------------------------------------------------
__global__ void k_prep(const float* __restrict__ W,
                       const float* __restrict__ att_s,
                       const float* __restrict__ att_d,
                       unsigned short* __restrict__ Bt,
                       float* __restrict__ WaS, float* __restrict__ WaD,
                       int* __restrict__ bcnt) {
  int gid = blockIdx.x * blockDim.x + threadIdx.x;
  if (gid < NBK) bcnt[gid] = 0;
  if (gid < 128 * 512) {
    int col = gid >> 9, k = gid & 511;
    float v = W[(k & 127) * 512 + (k >> 7) * 128 + col];
    _Float16 hv = (_Float16)v;
    Bt[col * 512 + k] = __builtin_bit_cast(unsigned short, hv);
  }
  if (gid < 512) {
    int k = gid >> 2, h = gid & 3;
    const float* wrow = W + k * 512 + h * 128;
    const float* as = att_s + h * 128;
    const float* ad = att_d + h * 128;
    float ss = 0.f, sd = 0.f;
    for (int c = 0; c < 128; ++c) { float w = wrow[c]; ss += w * as[c]; sd += w * ad[c]; }
    WaS[k * 4 + h] = ss;
    WaD[k * 4 + h] = sd;
  }
}

// ---------------------------------------------------------------------------
// Fused: x->fp16 xh + a_s/a_d (LDS-staged, 2 thr/node)  AND  pass-1 coarse
// binning of edge records (src | d_local<<16) into 196 bucket slots.
// ---------------------------------------------------------------------------
__global__ __launch_bounds__(256) void k_xcast_p1(const float* __restrict__ x,
                                                  const float* __restrict__ WaS,
                                                  const float* __restrict__ WaD,
                                                  const int* __restrict__ ei,
                                                  unsigned int* __restrict__ xh,
                                                  float* __restrict__ a_s,
                                                  float* __restrict__ a_d,
                                                  int* __restrict__ bcnt,
                                                  unsigned int* __restrict__ ebuf) {
  __shared__ unsigned long long D[128][33];
  __shared__ float4 wsl[128];
  __shared__ float4 wdl[128];
  __shared__ int cnt[NBK];
  __shared__ int gbase[NBK];
  int t = threadIdx.x;
  int nb = blockIdx.x * 128;
  if (t < 128) wsl[t] = ((const float4*)WaS)[t];
  else wdl[t - 128] = ((const float4*)WaD)[t - 128];
  for (int i = t; i < NBK; i += 256) cnt[i] = 0;

#pragma unroll
  for (int i = 0; i < 16; ++i) {
    int idx = t + i * 256;
    int n = idx >> 5, c4 = idx & 31;
    int gn = nb + n;
    float4 v = make_float4(0.f, 0.f, 0.f, 0.f);
    if (gn < NN) v = ((const float4*)x)[(size_t)gn * 32 + c4];
    unsigned int lo = pack2(v.x, v.y);
    unsigned int hi = pack2(v.z, v.w);
    if (gn < NN) ((uint2*)xh)[(size_t)gn * 32 + c4] = make_uint2(lo, hi);
    D[n][c4] = (unsigned long long)lo | ((unsigned long long)hi << 32);
  }
  __syncthreads();

  {
    int n = t >> 1, half = t & 1;
    float s0 = 0.f, s1 = 0.f, s2 = 0.f, s3 = 0.f;
    float d0 = 0.f, d1 = 0.f, d2 = 0.f, d3 = 0.f;
#pragma unroll
    for (int p = 0; p < 16; ++p) {
      int c4 = 2 * p + half;
      unsigned long long q = D[n][c4];
      f16x2 lo2 = __builtin_bit_cast(f16x2, (unsigned int)q);
      f16x2 hi2 = __builtin_bit_cast(f16x2, (unsigned int)(q >> 32));
      float f0 = (float)lo2[0], f1 = (float)lo2[1];
      float f2 = (float)hi2[0], f3 = (float)hi2[1];
      int c = c4 * 4;
      float4 w0 = wsl[c], w1 = wsl[c + 1], w2 = wsl[c + 2], w3 = wsl[c + 3];
      s0 += f0 * w0.x + f1 * w1.x + f2 * w2.x + f3 * w3.x;
      s1 += f0 * w0.y + f1 * w1.y + f2 * w2.y + f3 * w3.y;
      s2 += f0 * w0.z + f1 * w1.z + f2 * w2.z + f3 * w3.z;
      s3 += f0 * w0.w + f1 * w1.w + f2 * w2.w + f3 * w3.w;
      float4 v0 = wdl[c], v1 = wdl[c + 1], v2 = wdl[c + 2], v3 = wdl[c + 3];
      d0 += f0 * v0.x + f1 * v1.x + f2 * v2.x + f3 * v3.x;
      d1 += f0 * v0.y + f1 * v1.y + f2 * v2.y + f3 * v3.y;
      d2 += f0 * v0.z + f1 * v1.z + f2 * v2.z + f3 * v3.z;
      d3 += f0 * v0.w + f1 * v1.w + f2 * v2.w + f3 * v3.w;
    }
    s0 += __shfl_xor(s0, 1); s1 += __shfl_xor(s1, 1);
    s2 += __shfl_xor(s2, 1); s3 += __shfl_xor(s3, 1);
    d0 += __shfl_xor(d0, 1); d1 += __shfl_xor(d1, 1);
    d2 += __shfl_xor(d2, 1); d3 += __shfl_xor(d3, 1);
    int gn = nb + n;
    if (half == 0 && gn < NN) {
      *(float4*)(a_s + gn * 4) = make_float4(s0, s1, s2, s3);
      *(float4*)(a_d + gn * 4) = make_float4(d0, d1, d2, d3);
    }
  }

  // ---- pass 1: coarse dst-binning
  int e0 = blockIdx.x * CHX;
#pragma unroll
  for (int k = 0; k < CHX / 256; ++k) {
    int e = e0 + t + k * 256;
    if (e < ETOT) {
      int d = (e < EE) ? ei[EE + e] : (e - EE);
      atomicAdd(&cnt[d >> 8], 1);
    }
  }
  __syncthreads();
  for (int i = t; i < NBK; i += 256) {
    gbase[i] = (cnt[i] > 0) ? atomicAdd(&bcnt[i], cnt[i]) : 0;
    cnt[i] = 0;
  }
  __syncthreads();
#pragma unroll
  for (int k = 0; k < CHX / 256; ++k) {
    int e = e0 + t + k * 256;
    if (e < ETOT) {
      int s, d;
      if (e < EE) { s = ei[e]; d = ei[EE + e]; } else { s = d = e - EE; }
      int b = d >> 8;
      int idx = gbase[b] + atomicAdd(&cnt[b], 1);
      if (idx < CAP)
        ebuf[(size_t)b * CAP + idx] = (unsigned int)s | ((unsigned int)(d & 255) << 16);
    }
  }
}

// ---------------------------------------------------------------------------
// Pass 2: per 256-dst bucket -- local histogram, scan (writes rs), rank
// scatter in LDS, coalesced perm16.
// ---------------------------------------------------------------------------
__global__ __launch_bounds__(256) void k_p2(const unsigned int* __restrict__ ebuf,
                                            const int* __restrict__ bcnt,
                                            int* __restrict__ rs,
                                            unsigned short* __restrict__ perm16) {
  __shared__ int sb[256];
  __shared__ int loc[256];
  __shared__ int cnt[256];
  __shared__ unsigned short out16[CAP];
  __shared__ int basesh;
  int b = blockIdx.x, t = threadIdx.x;

  int v = (t < NBK) ? bcnt[t] : 0;
  sb[t] = v;
  __syncthreads();
  for (int off = 1; off < 256; off <<= 1) {
    int u = (t >= off) ? sb[t - off] : 0;
    __syncthreads();
    sb[t] += u;
    __syncthreads();
  }
  if (t == b) basesh = sb[t] - v;
  cnt[t] = 0;
  __syncthreads();

  int base = basesh;
  int m = min(bcnt[b], CAP);
  int d0 = b * 256;
  const unsigned int* rec = ebuf + (size_t)b * CAP;
  for (int i = t; i < m; i += 256) atomicAdd(&cnt[rec[i] >> 16], 1);
  __syncthreads();

  int c = cnt[t];
  sb[t] = c;
  __syncthreads();
  for (int off = 1; off < 256; off <<= 1) {
    int u = (t >= off) ? sb[t - off] : 0;
    __syncthreads();
    sb[t] += u;
    __syncthreads();
  }
  int ex = sb[t] - c;
  loc[t] = ex;
  int gi = d0 + t;
  if (gi < NN) rs[gi] = base + ex;
  if (b == NBK - 1 && t == 0) rs[NN] = base + m;
  cnt[t] = 0;
  __syncthreads();

  for (int i = t; i < m; i += 256) {
    unsigned int r = rec[i];
    int dl = r >> 16;
    int rk = atomicAdd(&cnt[dl], 1);
    out16[loc[dl] + rk] = (unsigned short)(r & 0xffffu);
  }
  __syncthreads();
  for (int i = t; i < m; i += 256) perm16[base + i] = out16[i];
}

// ---------------------------------------------------------------------------
// Aggregation in INPUT space (split structure, R5-proven): 256-thr blocks,
// 4 waves, ONE node per wave, grid 12500 -> fine-grained load balance.
// Weights single-shot (deg<=64), byte offsets pre-shifted in LDS, 8-deep
// gather ILP. z written fp16 to global.
// ---------------------------------------------------------------------------
__global__ __launch_bounds__(256) void k_aggz(const float* __restrict__ a_s,
                                              const float* __restrict__ a_d,
                                              const unsigned int* __restrict__ xh,
                                              const int* __restrict__ rs,
                                              const unsigned short* __restrict__ perm16,
                                              unsigned int* __restrict__ zbuf) {
  __shared__ unsigned int off_s[4][MAXD];
  __shared__ float4 w_s[4][MAXD];
  int wave = threadIdx.x >> 6, lane = threadIdx.x & 63;
  int n = blockIdx.x * 4 + wave;
  float4 ad = *(const float4*)(a_d + n * 4);
  int s = rs[n], e = rs[n + 1];
  int deg = e - s;
  bool fast = (deg <= MAXD);

  float t0 = 0.f, t1 = 0.f, t2 = 0.f, t3 = 0.f;
  if (fast) {
    if (lane < deg) {
      int sn = perm16[s + lane];
      off_s[wave][lane] = (unsigned int)sn * 256u;  // byte offset into xh
      float4 as = *(const float4*)(a_s + sn * 4);
      float e0 = __expf(lrelu(as.x + ad.x));
      float e1 = __expf(lrelu(as.y + ad.y));
      float e2 = __expf(lrelu(as.z + ad.z));
      float e3 = __expf(lrelu(as.w + ad.w));
      w_s[wave][lane] = make_float4(e0, e1, e2, e3);
      t0 = e0; t1 = e1; t2 = e2; t3 = e3;
    }
  } else {
    for (int j = lane; j < deg; j += 64) {
      int sn = perm16[s + j];
      float4 as = *(const float4*)(a_s + sn * 4);
      t0 += __expf(lrelu(as.x + ad.x)); t1 += __expf(lrelu(as.y + ad.y));
      t2 += __expf(lrelu(as.z + ad.z)); t3 += __expf(lrelu(as.w + ad.w));
    }
  }
#pragma unroll
  for (int off = 32; off; off >>= 1) {
    t0 += __shfl_xor(t0, off); t1 += __shfl_xor(t1, off);
    t2 += __shfl_xor(t2, off); t3 += __shfl_xor(t3, off);
  }
  float sc0 = 0.25f / (t0 + 1e-16f), sc1 = 0.25f / (t1 + 1e-16f);
  float sc2 = 0.25f / (t2 + 1e-16f), sc3 = 0.25f / (t3 + 1e-16f);
  __builtin_amdgcn_wave_barrier();  // intra-wave LDS ordering fence

  const char* xb = (const char*)xh;
  int lb = lane * 4;
  f32x2 za0 = {0.f, 0.f}, za1 = {0.f, 0.f}, za2 = {0.f, 0.f}, za3 = {0.f, 0.f};
  if (fast) {
    int j = 0;
    for (; j + 8 <= deg; j += 8) {
      unsigned int u[8];
#pragma unroll
      for (int k = 0; k < 8; ++k)
        u[k] = *(const unsigned int*)(xb + off_s[wave][j + k] + lb);
#pragma unroll
      for (int k = 0; k < 8; ++k) {
        float4 w = w_s[wave][j + k];
        f16x2 p = __builtin_bit_cast(f16x2, u[k]);
        f32x2 xv = {(float)p[0], (float)p[1]};
        za0 += w.x * xv; za1 += w.y * xv; za2 += w.z * xv; za3 += w.w * xv;
      }
    }
    if (j + 4 <= deg) {
      unsigned int u[4];
#pragma unroll
      for (int k = 0; k < 4; ++k)
        u[k] = *(const unsigned int*)(xb + off_s[wave][j + k] + lb);
#pragma unroll
      for (int k = 0; k < 4; ++k) {
        float4 w = w_s[wave][j + k];
        f16x2 p = __builtin_bit_cast(f16x2, u[k]);
        f32x2 xv = {(float)p[0], (float)p[1]};
        za0 += w.x * xv; za1 += w.y * xv; za2 += w.z * xv; za3 += w.w * xv;
      }
      j += 4;
    }
    for (; j < deg; ++j) {
      float4 w = w_s[wave][j];
      unsigned int u = *(const unsigned int*)(xb + off_s[wave][j] + lb);
      f16x2 p = __builtin_bit_cast(f16x2, u);
      f32x2 xv = {(float)p[0], (float)p[1]};
      za0 += w.x * xv; za1 += w.y * xv; za2 += w.z * xv; za3 += w.w * xv;
    }
  } else {
    for (int j = 0; j < deg; ++j) {
      int sn = perm16[s + j];
      float4 as = *(const float4*)(a_s + sn * 4);
      float w0 = __expf(lrelu(as.x + ad.x));
      float w1 = __expf(lrelu(as.y + ad.y));
      float w2 = __expf(lrelu(as.z + ad.z));
      float w3 = __expf(lrelu(as.w + ad.w));
      unsigned int u = xh[sn * 64 + lane];
      f16x2 p = __builtin_bit_cast(f16x2, u);
      f32x2 xv = {(float)p[0], (float)p[1]};
      za0 += w0 * xv; za1 += w1 * xv; za2 += w2 * xv; za3 += w3 * xv;
    }
  }

  zbuf[n * 256 + 0 * 64 + lane] = pack2(za0[0] * sc0, za0[1] * sc0);
  zbuf[n * 256 + 1 * 64 + lane] = pack2(za1[0] * sc1, za1[1] * sc1);
  zbuf[n * 256 + 2 * 64 + lane] = pack2(za2[0] * sc2, za2[1] * sc2);
  zbuf[n * 256 + 3 * 64 + lane] = pack2(za3[0] * sc3, za3[1] * sc3);
}

// ---------------------------------------------------------------------------
// GEMM: out[N][128] fp32 = Z[N][512] (fp16) @ Bt^T, MFMA 16x16x32 f16.
// Block tile 64x128, 4 waves (2x2 of 32x64), K staged 128/step, swizzled LDS.
// ---------------------------------------------------------------------------
__global__ __launch_bounds__(256) void k_gemmz(const unsigned short* __restrict__ zbuf,
                                               const unsigned short* __restrict__ Bt,
                                               float* __restrict__ out) {
  __shared__ u32x4 Al[1024];
  __shared__ u32x4 Bl[2048];
  int m0 = blockIdx.x * 64;
  int wave = threadIdx.x >> 6, lane = threadIdx.x & 63;
  int wm = (wave >> 1) * 32, wn = (wave & 1) * 64;
  int lr = lane & 15, lk = lane >> 4;

  f32x4 acc[2][4];
#pragma unroll
  for (int mi = 0; mi < 2; ++mi)
#pragma unroll
    for (int ni = 0; ni < 4; ++ni) acc[mi][ni] = (f32x4){0.f, 0.f, 0.f, 0.f};

  for (int t = 0; t < 4; ++t) {
#pragma unroll
    for (int i = 0; i < 4; ++i) {
      int id = threadIdx.x + 256 * i;
      int row = id >> 4, kc = id & 15;
      int grow = m0 + row;
      u32x4 v = {0u, 0u, 0u, 0u};
      if (grow < NN) v = *(const u32x4*)((const char*)zbuf + grow * 1024 + t * 256 + kc * 16);
      Al[row * 16 + (kc ^ (row & 7))] = v;
    }
#pragma unroll
    for (int i = 0; i < 8; ++i) {
      int id = threadIdx.x + 256 * i;
      int col = id >> 4, kc = id & 15;
      u32x4 v = *(const u32x4*)((const char*)Bt + col * 1024 + t * 256 + kc * 16);
      Bl[col * 16 + (kc ^ (col & 7))] = v;
    }
    __syncthreads();
#pragma unroll
    for (int ks = 0; ks < 4; ++ks) {
      f16x8 af[2], bf[4];
#pragma unroll
      for (int mi = 0; mi < 2; ++mi) {
        int r = wm + mi * 16 + lr;
        af[mi] = __builtin_bit_cast(f16x8, Al[r * 16 + ((ks * 4 + lk) ^ (r & 7))]);
      }
#pragma unroll
      for (int ni = 0; ni < 4; ++ni) {
        int c = wn + ni * 16 + lr;
        bf[ni] = __builtin_bit_cast(f16x8, Bl[c * 16 + ((ks * 4 + lk) ^ (c & 7))]);
      }
#pragma unroll
      for (int mi = 0; mi < 2; ++mi)
#pragma unroll
        for (int ni = 0; ni < 4; ++ni)
          acc[mi][ni] = __builtin_amdgcn_mfma_f32_16x16x32_f16(af[mi], bf[ni], acc[mi][ni], 0, 0, 0);
    }
    __syncthreads();
  }

  int cr = lk * 4;
#pragma unroll
  for (int mi = 0; mi < 2; ++mi) {
#pragma unroll
    for (int j = 0; j < 4; ++j) {
      int row = m0 + wm + mi * 16 + cr + j;
      if (row < NN) {
#pragma unroll
        for (int ni = 0; ni < 4; ++ni) {
          int col = wn + ni * 16 + lr;
          out[row * 128 + col] = acc[mi][ni][j];
        }
      }
    }
  }
}

// ---------------------------------------------------------------------------
extern "C" void kernel_launch(void* const* d_in, const int* in_sizes, int n_in,
                              void* d_out, int out_size, void* d_ws, size_t ws_size,
                              hipStream_t stream) {
  const float* x = (const float*)d_in[0];
  const int* ei = (const int*)d_in[1];
  const float* W = (const float*)d_in[2];
  const float* att_s = (const float*)d_in[3];
  const float* att_d = (const float*)d_in[4];
  float* out = (float*)d_out;
  char* ws = (char*)d_ws;

  unsigned int* xh = (unsigned int*)(ws + 0);                 // 12,800,000 B
  unsigned int* zbuf = (unsigned int*)(ws + 12800000);        // 51,200,000 B
  unsigned int* ebuf = (unsigned int*)(ws + 12800000);        //  4,816,896 B (aliased; dead before zbuf)
  unsigned short* Bt = (unsigned short*)(ws + 64000000);      //    131,072 B
  float* WaS = (float*)(ws + 64131072);                       //      2,048 B
  float* WaD = (float*)(ws + 64133120);                       //      2,048 B
  float* a_s = (float*)(ws + 64135168);                       //    800,000 B
  float* a_d = (float*)(ws + 64935168);                       //    800,000 B
  int* rs = (int*)(ws + 65735168);                            //    200,192 B
  int* bcnt = (int*)(ws + 65935360);                          //      1,024 B
  unsigned short* perm16 = (unsigned short*)(ws + 65936384);  //  1,700,000 B

  k_prep<<<256, 256, 0, stream>>>(W, att_s, att_d, Bt, WaS, WaD, bcnt);
  k_xcast_p1<<<(NN + 127) / 128, 256, 0, stream>>>(x, WaS, WaD, ei, xh, a_s, a_d, bcnt, ebuf);
  k_p2<<<NBK, 256, 0, stream>>>(ebuf, bcnt, rs, perm16);
  k_aggz<<<NN / 4, 256, 0, stream>>>(a_s, a_d, xh, rs, perm16, zbuf);
  k_gemmz<<<(NN + 63) / 64, 256, 0, stream>>>((const unsigned short*)zbuf, Bt, out);
}